// Round 13
// baseline (875.363 us; speedup 1.0000x reference)
//
#include <hip/hip_runtime.h>
#include <hip/hip_bf16.h>

typedef unsigned short u16;
typedef unsigned int u32;

static __device__ __forceinline__ float us2f(u16 u) {
    return __uint_as_float(((u32)u) << 16);
}
static __device__ __forceinline__ u16 f2bu(float f) {  // RNE
    u32 u = __float_as_uint(f);
    return (u16)((u + 0x7fffu + ((u >> 16) & 1u)) >> 16);
}

typedef __attribute__((ext_vector_type(8))) __bf16 bf16x8;
typedef __attribute__((ext_vector_type(4))) float f32x4;

// async global->LDS DMA, 16B per lane. LDS dest must be wave-uniform base;
// HW writes lane l at base + l*16 (linear).
static __device__ __forceinline__ void async16(const u16* g, u16* l) {
    __builtin_amdgcn_global_load_lds(
        (const __attribute__((address_space(1))) unsigned int*)g,
        (__attribute__((address_space(3))) unsigned int*)l, 16, 0, 0);
}

__global__ void fill_sentinel(float* out, int n, float val) {
    int g = blockIdx.x * 256 + threadIdx.x;
    if (g < n) out[g] = val;
}

// ============================================================
// prep1: transpose prim_w (blocks 0..255) + zero x3m head (2292 blocks)
// + build conv1 MFMA weights wc1b [3][256][32] bf16 (block 2548).
// ============================================================
__global__ __launch_bounds__(256) void prep1(const float* __restrict__ pw,
    u16* __restrict__ wt, float* __restrict__ x3m,
    const float* __restrict__ c1w, u16* __restrict__ wc1b)
{
    __shared__ u16 wl[81 * 258];
    const int bid = blockIdx.x, tid = threadIdx.x;
    if (bid < 256) {
        const float* ws = pw + (size_t)bid * 20736;
        for (int idx = tid; idx < 20736; idx += 256) {
            const int cc = idx / 81, kk = idx - cc * 81;
            wl[kk * 258 + cc] = f2bu(ws[idx]);
        }
        __syncthreads();
        u16* wo = wt + (size_t)bid * 20736;
        for (int q = tid; q < 20736; q += 256)
            wo[q] = wl[(q >> 8) * 258 + (q & 255)];
    } else if (bid < 2548) {
        float4 z = {0.f, 0.f, 0.f, 0.f};
        reinterpret_cast<float4*>(x3m)[(size_t)(bid - 256) * 256 + tid] = z;
    } else {
        for (int idx = tid; idx < 24576; idx += 256) {
            const int s = idx >> 13, rem = idx & 8191;
            const int n = rem >> 5, kk = rem & 31;
            const int k = s * 32 + kk;
            wc1b[idx] = (k < 81) ? f2bu(c1w[n * 81 + k]) : (u16)0;
        }
    }
}

// ============================================================
// prep2 (post-prim): dw->bf16 + zero preactD.
// ============================================================
__global__ __launch_bounds__(256) void prep2(const float* __restrict__ dw,
    u16* __restrict__ dwb_t, float* __restrict__ preactD)
{
    const int bid = blockIdx.x, tid = threadIdx.x;
    if (bid < 5760) {
        const int g = bid * 256 + tid;   // 1,474,560
        dwb_t[g] = f2bu(dw[g]);
    } else {
        float4 z = {0.f, 0.f, 0.f, 0.f};
        reinterpret_cast<float4*>(preactD)[(size_t)(bid - 5760) * 256 + tid] = z;
    }
}

// ============================================================
// Kernel 1 (r11, verified): conv1 via MFMA, hi+lo bf16 split.
// ============================================================
__global__ __launch_bounds__(256, 2) void conv1_mfma(const float* __restrict__ x,
    const u16* __restrict__ wc1b, const float* __restrict__ bias, u16* __restrict__ h)
{
    __shared__ float xs[1568];
    const int tid = threadIdx.x;
    const int mBase = blockIdx.x * 128;          // 800 blocks
    const int b0 = mBase / 400;
    const int lane = tid & 63, wv = tid >> 6;
    const int wm = wv >> 1, wn = wv & 1;
    const int lcol = lane & 15, lquad = lane >> 4;

    {   // stage the (<=2) source images
        const int b1 = (b0 + 1 < 256) ? b0 + 1 : b0;
        for (int i = tid; i < 784; i += 256) {
            xs[i] = x[b0 * 784 + i];
            xs[784 + i] = x[b1 * 784 + i];
        }
    }
    __syncthreads();

    float bj[8];
    #pragma unroll
    for (int j = 0; j < 8; ++j) bj[j] = bias[wn * 128 + j * 16 + lcol];

    int xbase[4];
    #pragma unroll
    for (int i = 0; i < 4; ++i) {
        const int m = mBase + wm * 64 + i * 16 + lcol;
        const int img = (m / 400) - b0;
        const int rr = m % 400;
        const int iy = rr / 20, ix = rr - iy * 20;
        xbase[i] = img * 784 + iy * 28 + ix;
    }

    f32x4 acc[4][8];
    #pragma unroll
    for (int i = 0; i < 4; ++i)
        #pragma unroll
        for (int j = 0; j < 8; ++j) acc[i][j] = (f32x4){0.f, 0.f, 0.f, 0.f};

    #pragma unroll 1
    for (int s = 0; s < 3; ++s) {
        bf16x8 bfr[8];
        const u16* bp = wc1b + s * 8192 + (wn * 128 + lcol) * 32 + lquad * 8;
        #pragma unroll
        for (int j = 0; j < 8; ++j)
            bfr[j] = *reinterpret_cast<const bf16x8*>(bp + j * 512);

        bf16x8 ah[4], al[4];
        #pragma unroll
        for (int i = 0; i < 4; ++i) {
            union { bf16x8 v; u16 u[8]; } H, L;
            #pragma unroll
            for (int e = 0; e < 8; ++e) {
                int k = s * 32 + lquad * 8 + e;
                if (k > 80) k = 0;
                const int dy = k / 9, dx = k - dy * 9;
                const float xv = xs[xbase[i] + dy * 28 + dx];
                const u16 hu = f2bu(xv);
                H.u[e] = hu;
                L.u[e] = f2bu(xv - us2f(hu));
            }
            ah[i] = H.v; al[i] = L.v;
        }
        #pragma unroll
        for (int i = 0; i < 4; ++i)
            #pragma unroll
            for (int j = 0; j < 8; ++j) {
                acc[i][j] = __builtin_amdgcn_mfma_f32_16x16x32_bf16(ah[i], bfr[j], acc[i][j], 0, 0, 0);
                acc[i][j] = __builtin_amdgcn_mfma_f32_16x16x32_bf16(al[i], bfr[j], acc[i][j], 0, 0, 0);
            }
    }

    #pragma unroll
    for (int i = 0; i < 4; ++i) {
        const int mrow = mBase + wm * 64 + i * 16 + lquad * 4;
        #pragma unroll
        for (int j = 0; j < 8; ++j) {
            const int ncol = wn * 128 + j * 16 + lcol;
            #pragma unroll
            for (int r = 0; r < 4; ++r)
                h[(size_t)(mrow + r) * 256 + ncol] = f2bu(fmaxf(acc[i][j][r] + bj[j], 0.f));
        }
    }
}

// ============================================================
// Kernel 4: primary-caps GEMM — r5 config (157 us, verified x5 runs).
// r12 BM=256 regressed (1 block/CU barrier serialization + 40 idle CUs).
// prim is at its structural floor; frozen.
// ============================================================
__global__ __launch_bounds__(256, 2) void prim_gemm_split(const u16* __restrict__ h,
    const u16* __restrict__ wT, float* __restrict__ pm)
{
    __shared__ u16 As[3 * 4096];   // 3 x 8 KB  (128 rows x 32 u16)
    __shared__ u16 Bs[3 * 8192];   // 3 x 16 KB (256 rows x 32 u16)
    const int tid = threadIdx.x;
    const int split = blockIdx.y;
    const int mBase = blockIdx.x * 128;          // 72 m-tiles
    const int lane = tid & 63, wv = tid >> 6;
    const int swzq = (tid & 3) ^ ((lane >> 3) & 3);
    const int rA = wv * 32 + (lane >> 2);
    const int rB = wv * 64 + (lane >> 2);
    int mA0 = mBase + rA;
    int bA0 = mA0 / 36, rr0 = mA0 % 36;
    const int aBase0 = ((bA0 * 20 + 2 * (rr0 / 6)) * 20 + 2 * (rr0 % 6)) * 256 + swzq * 8;
    int mA1 = mA0 + 16;
    int bA1 = mA1 / 36, rr1 = mA1 % 36;
    const int aBase1 = ((bA1 * 20 + 2 * (rr1 / 6)) * 20 + 2 * (rr1 % 6)) * 256 + swzq * 8;
    const u16* bp0 = wT + (size_t)rB * 20736 + swzq * 8;

    int kglob = split * 3456;                  // 20736 / 6
    int ky = kglob / 2304; int krem = kglob - ky * 2304;
    int kx = krem >> 8; int c0 = krem & 255;

    f32x4 acc[4][8];
    #pragma unroll
    for (int i = 0; i < 4; ++i)
        #pragma unroll
        for (int j = 0; j < 8; ++j) acc[i][j] = (f32x4){0.f, 0.f, 0.f, 0.f};

    const int wm = wv >> 1, wn = wv & 1;
    const int lcol = lane & 15, lquad = lane >> 4;
    const int rswz = (lquad ^ ((lcol >> 1) & 3)) * 8;
    const u16* Arow = As + (wm * 64 + lcol) * 32 + rswz;
    const u16* Brow = Bs + (wn * 128 + lcol) * 32 + rswz;
    u16* aD = As + wv * 1024;
    u16* bD = Bs + wv * 2048;

    #define STAGE(sel)  do {                                                   \
        const int koffA = (ky * 20 + kx) * 256 + c0;                           \
        async16(h + aBase0 + koffA, aD + (sel) * 4096);                        \
        async16(h + aBase1 + koffA, aD + (sel) * 4096 + 512);                  \
        async16(bp0 + kglob,          bD + (sel) * 8192);                      \
        async16(bp0 + 331776 + kglob, bD + (sel) * 8192 + 512);               \
        async16(bp0 + 663552 + kglob, bD + (sel) * 8192 + 1024);              \
        async16(bp0 + 995328 + kglob, bD + (sel) * 8192 + 1536);              \
        kglob += 32; c0 += 32;                                                 \
        if (c0 == 256) { c0 = 0; if (++kx == 9) { kx = 0; ++ky; } }            \
    } while (0)

    #define COMPUTE(sel)  do {                                                 \
        const u16* Ab = Arow + (sel) * 4096;                                   \
        const u16* Bb = Brow + (sel) * 8192;                                   \
        bf16x8 af[4], bfr[8];                                                  \
        _Pragma("unroll")                                                      \
        for (int i = 0; i < 4; ++i)                                            \
            af[i] = *reinterpret_cast<const bf16x8*>(Ab + i * 512);            \
        _Pragma("unroll")                                                      \
        for (int j = 0; j < 8; ++j)                                            \
            bfr[j] = *reinterpret_cast<const bf16x8*>(Bb + j * 512);           \
        __builtin_amdgcn_s_setprio(1);                                         \
        _Pragma("unroll")                                                      \
        for (int i = 0; i < 4; ++i)                                            \
            _Pragma("unroll")                                                  \
            for (int j = 0; j < 8; ++j)                                        \
                acc[i][j] = __builtin_amdgcn_mfma_f32_16x16x32_bf16(af[i], bfr[j], acc[i][j], 0, 0, 0); \
        __builtin_amdgcn_s_setprio(0);                                         \
    } while (0)

    // 108 tiles. Prologue: tiles 0,1 -> bufs 0,1 (12 DMAs in flight).
    STAGE(0);
    STAGE(1);
    int cb = 0, sb = 2;
    #pragma unroll 1
    for (int kt = 0; kt < 106; ++kt) {
        STAGE(sb);                                        // tile kt+2 (18 in flight)
        asm volatile("s_waitcnt vmcnt(12)" ::: "memory"); // 6 oldest (tile kt) done
        __builtin_amdgcn_s_barrier();
        __builtin_amdgcn_sched_barrier(0);
        COMPUTE(cb);
        __builtin_amdgcn_sched_barrier(0);
        __builtin_amdgcn_s_barrier();
        __builtin_amdgcn_sched_barrier(0);
        cb = (cb == 2) ? 0 : cb + 1;
        sb = (sb == 2) ? 0 : sb + 1;
    }
    asm volatile("s_waitcnt vmcnt(6)" ::: "memory");
    __builtin_amdgcn_s_barrier();
    __builtin_amdgcn_sched_barrier(0);
    COMPUTE(1);
    __builtin_amdgcn_sched_barrier(0);
    asm volatile("s_waitcnt vmcnt(0)" ::: "memory");
    __builtin_amdgcn_s_barrier();
    __builtin_amdgcn_sched_barrier(0);
    COMPUTE(2);
    #undef STAGE
    #undef COMPUTE

    #pragma unroll
    for (int i = 0; i < 4; ++i) {
        const int mrow = mBase + wm * 64 + i * 16 + lquad * 4;
        #pragma unroll
        for (int j = 0; j < 8; ++j) {
            const int ncol = wn * 128 + j * 16 + lcol;
            #pragma unroll
            for (int r = 0; r < 4; ++r)
                unsafeAtomicAdd(&pm[(size_t)(mrow + r) * 256 + ncol], acc[i][j][r]);
        }
    }
}

// ============================================================
// Kernel 6: votes materialization with FUSED squash.
// ============================================================
__global__ __launch_bounds__(192) void votes_gemm(const float* __restrict__ x3m,
    const float* __restrict__ pb, const u16* __restrict__ dwb_t,
    u16* __restrict__ votes, int hb)
{
    __shared__ float dws[8 * 1280];    // [i_l][a][ot] 40 KB
    __shared__ float x3s[64 * 64];     // [b_l][i_l][a] 16 KB
    __shared__ float pbs[256];
    const int ic = blockIdx.x * 8, bc = blockIdx.y * 64;
    const int tid = threadIdx.x;
    for (int q = tid; q < 256; q += 192) pbs[q] = pb[q];
    for (int q = tid; q < 10240; q += 192)
        dws[q] = us2f(dwb_t[(size_t)ic * 1280 + q]);
    __syncthreads();
    for (int g = tid; g < 512; g += 192) {
        const int b_l = g >> 3, i_l = g & 7;
        const int i = ic + i_l, cap = i / 36, p = i - cap * 36;
        const float* src = &x3m[((size_t)(hb + bc + b_l) * 36 + p) * 256 + cap * 8];
        float v[8]; float n2 = 0.f;
        #pragma unroll
        for (int a = 0; a < 8; ++a) {
            v[a] = src[a] * (1.f / 32.f) + pbs[cap * 8 + a];
            n2 += v[a] * v[a];
        }
        const float scale = (n2 / (1.f + n2)) * rsqrtf(n2 + 1e-9f);
        #pragma unroll
        for (int a = 0; a < 8; ++a)
            x3s[b_l * 64 + i_l * 8 + a] = v[a] * scale;
    }
    __syncthreads();
    if (tid < 160) {
        const int ot = tid;
        float dwr[8][8];
        #pragma unroll
        for (int i_l = 0; i_l < 8; ++i_l)
            #pragma unroll
            for (int a = 0; a < 8; ++a)
                dwr[i_l][a] = dws[i_l * 1280 + a * 160 + ot];
        #pragma unroll 1
        for (int b_l = 0; b_l < 64; ++b_l) {
            u16 ob[8];
            #pragma unroll
            for (int i_l = 0; i_l < 8; ++i_l) {
                const float* xp = &x3s[b_l * 64 + i_l * 8];
                float v = 0.f;
                #pragma unroll
                for (int a = 0; a < 8; ++a) v += xp[a] * dwr[i_l][a];
                ob[i_l] = f2bu(v);
            }
            uint4 o4;
            o4.x = (u32)ob[0] | ((u32)ob[1] << 16);
            o4.y = (u32)ob[2] | ((u32)ob[3] << 16);
            o4.z = (u32)ob[4] | ((u32)ob[5] << 16);
            o4.w = (u32)ob[6] | ((u32)ob[7] << 16);
            *reinterpret_cast<uint4*>(&votes[((size_t)(bc + b_l) * 160 + ot) * 1152 + ic]) = o4;
        }
    }
}

// ============================================================
// Kernel 7 (r13): ALL 3 routing iterations in ONE kernel, one block
// per b_l (grid 128/half, 512 threads). pD (160 f) and logits (46 KB)
// live in LDS — no global logits, no atomics, pD2 written once.
// votes[b_l] streamed 3x in 9 chunks of 128 i (double-buffered,
// reg-prefetch). LDS row stride 130 u16 (65 words, odd -> conflict-free
// lane-per-ot reads); u-calc maps tid=(i<<2)|g, g sums 40 ot, 4-lane
// shfl combine (banks: 8g + i/2 -> 32 distinct, conflict-free).
// Replaces 6 routing_fused dispatches; votes traffic 283->141 MB.
// ============================================================
__global__ __launch_bounds__(512, 1) void routing_all(const u16* __restrict__ votes,
    const float* __restrict__ db, float* __restrict__ pD2, int hb)
{
    __shared__ u16 vch[2][160 * 130];      // 83,200 B
    __shared__ float lg[11520];            // 46,080 B (logits [1152][10])
    __shared__ float route_s[1280];        // 5,120 B  ([128 i][10])
    __shared__ float act_s[160];
    const int b_l = blockIdx.x, gb = hb + b_l;
    const int tid = threadIdx.x;
    const u16* vb = votes + (size_t)b_l * 184320;   // 160*1152
    const int iq = tid >> 2, gq = tid & 3;
    const float dbv = (tid < 160) ? db[tid] : 0.f;
    uint4 pf[5];

#define LOADC(c) do {                                                          \
    _Pragma("unroll")                                                          \
    for (int r = 0; r < 5; ++r) {                                              \
        const int q = tid + r * 512;                                           \
        pf[r] = *reinterpret_cast<const uint4*>(                               \
            vb + (q >> 4) * 1152 + (c) * 128 + (q & 15) * 8);                  \
    } } while (0)

#define WRITEC(buf) do {                                                       \
    _Pragma("unroll")                                                          \
    for (int r = 0; r < 5; ++r) {                                              \
        const int q = tid + r * 512;                                           \
        u32* d = reinterpret_cast<u32*>(&vch[buf][(q >> 4) * 130 + (q & 15) * 8]); \
        d[0] = pf[r].x; d[1] = pf[r].y; d[2] = pf[r].z; d[3] = pf[r].w;        \
    } } while (0)

#define SQUASH_TO_ACT(preexpr) do {                                            \
    if (tid < 160) {                                                           \
        float pre = (preexpr) + dbv;                                           \
        float sq = pre * pre;                                                  \
        sq += __shfl_xor(sq, 1); sq += __shfl_xor(sq, 2);                      \
        sq += __shfl_xor(sq, 4); sq += __shfl_xor(sq, 8);                      \
        act_s[tid] = pre * (sq / (1.f + sq)) * rsqrtf(sq + 1e-9f);             \
    }                                                                          \
    __syncthreads();                                                           \
} while (0)

    // ---------------- pass 1: act0 (uniform route = 0.1 * sum) ----------------
    float accP = 0.f;
    LOADC(0); WRITEC(0); __syncthreads();
    #pragma unroll 1
    for (int c = 0; c < 9; ++c) {
        if (c < 8) LOADC(c + 1);
        if (tid < 160) {
            const u16* vrow = &vch[c & 1][tid * 130];
            float s = 0.f;
            #pragma unroll 8
            for (int i = 0; i < 128; ++i) s += us2f(vrow[i]);
            accP += s;
        }
        if (c < 8) WRITEC((c + 1) & 1);
        __syncthreads();
    }
    SQUASH_TO_ACT(0.1f * accP);

    // ---------------- pass 2: logits = votes.act0; route; pD1 ----------------
    float pP = 0.f;
    LOADC(0); WRITEC(0); __syncthreads();
    #pragma unroll 1
    for (int c = 0; c < 9; ++c) {
        if (c < 8) LOADC(c + 1);
        {
            const u16* vcol = &vch[c & 1][gq * 5200 + iq];   // gq*40*130
            float u[10];
            #pragma unroll
            for (int k = 0; k < 10; ++k) u[k] = 0.f;
            #pragma unroll 8
            for (int t = 0; t < 40; ++t) {
                const int ot = gq * 40 + t;
                u[ot >> 4] += us2f(vcol[t * 130]) * act_s[ot];
            }
            #pragma unroll
            for (int k = 0; k < 10; ++k) {
                u[k] += __shfl_xor(u[k], 1);
                u[k] += __shfl_xor(u[k], 2);
            }
            const int gi = c * 128 + iq;
            if (gq == 0) {
                #pragma unroll
                for (int k = 0; k < 10; ++k) lg[gi * 10 + k] = u[k];
            }
            float mx = -1e30f;
            #pragma unroll
            for (int k = 0; k < 10; ++k) mx = fmaxf(mx, u[k]);
            float s = 0.f;
            #pragma unroll
            for (int k = 0; k < 10; ++k) { u[k] = __expf(u[k] - mx); s += u[k]; }
            const float inv = 1.f / s;
            if (gq == 0) {
                #pragma unroll
                for (int k = 0; k < 10; ++k) route_s[iq * 10 + k] = u[k] * inv;
            }
        }
        __syncthreads();
        if (tid < 160) {
            const int o = tid >> 4;
            const u16* vrow = &vch[c & 1][tid * 130];
            float s = 0.f;
            #pragma unroll 8
            for (int i = 0; i < 128; ++i) s += route_s[i * 10 + o] * us2f(vrow[i]);
            pP += s;
        }
        if (c < 8) WRITEC((c + 1) & 1);
        __syncthreads();
    }
    SQUASH_TO_ACT(pP);

    // ---------------- pass 3: logits += votes.act1; route; pD2 ----------------
    float pP2 = 0.f;
    LOADC(0); WRITEC(0); __syncthreads();
    #pragma unroll 1
    for (int c = 0; c < 9; ++c) {
        if (c < 8) LOADC(c + 1);
        {
            const u16* vcol = &vch[c & 1][gq * 5200 + iq];
            float u[10];
            #pragma unroll
            for (int k = 0; k < 10; ++k) u[k] = 0.f;
            #pragma unroll 8
            for (int t = 0; t < 40; ++t) {
                const int ot = gq * 40 + t;
                u[ot >> 4] += us2f(vcol[t * 130]) * act_s[ot];
            }
            #pragma unroll
            for (int k = 0; k < 10; ++k) {
                u[k] += __shfl_xor(u[k], 1);
                u[k] += __shfl_xor(u[k], 2);
            }
            const int gi = c * 128 + iq;
            #pragma unroll
            for (int k = 0; k < 10; ++k) u[k] += lg[gi * 10 + k];
            float mx = -1e30f;
            #pragma unroll
            for (int k = 0; k < 10; ++k) mx = fmaxf(mx, u[k]);
            float s = 0.f;
            #pragma unroll
            for (int k = 0; k < 10; ++k) { u[k] = __expf(u[k] - mx); s += u[k]; }
            const float inv = 1.f / s;
            if (gq == 0) {
                #pragma unroll
                for (int k = 0; k < 10; ++k) route_s[iq * 10 + k] = u[k] * inv;
            }
        }
        __syncthreads();
        if (tid < 160) {
            const int o = tid >> 4;
            const u16* vrow = &vch[c & 1][tid * 130];
            float s = 0.f;
            #pragma unroll 8
            for (int i = 0; i < 128; ++i) s += route_s[i * 10 + o] * us2f(vrow[i]);
            pP2 += s;
        }
        if (c < 8) WRITEC((c + 1) & 1);
        __syncthreads();
    }
    if (tid < 160)
        pD2[(size_t)gb * 160 + tid] = pP2;
#undef LOADC
#undef WRITEC
#undef SQUASH_TO_ACT
}

// ============================================================
// Kernel 10: dense layer, 4 rows/block. When db2 != nullptr, layer-1
// mode — in = RAW pD2; squash computed inline; digit written to dout
// by blockIdx.y==0 blocks.
// ============================================================
__global__ __launch_bounds__(256) void mlp_layer(const float* __restrict__ in,
    const float* __restrict__ maskY, const float* __restrict__ w,
    const float* __restrict__ bias, float* __restrict__ outp, int K, int N, int mode,
    const float* __restrict__ db2, float* __restrict__ dout)
{
    __shared__ float ins[4 * 1024];
    __shared__ float scl[40];
    const int b0 = blockIdx.x * 4;
    const int n = blockIdx.y * 256 + threadIdx.x;
    if (db2) {
        if (threadIdx.x < 40) {
            const int b_l = threadIdx.x / 10, o = threadIdx.x - b_l * 10;
            const float* pp = &in[(size_t)(b0 + b_l) * 160 + o * 16];
            float n2 = 0.f;
            #pragma unroll
            for (int t = 0; t < 16; ++t) {
                float pv = pp[t] + db2[o * 16 + t];
                n2 += pv * pv;
            }
            scl[threadIdx.x] = (n2 / (1.f + n2)) * rsqrtf(n2 + 1e-9f);
        }
        __syncthreads();
        for (int idx = threadIdx.x; idx < 4 * 160; idx += 256) {
            const int b_l = idx / 160, j = idx - b_l * 160;
            float a = (in[(size_t)(b0 + b_l) * 160 + j] + db2[j]) * scl[b_l * 10 + (j >> 4)];
            if (blockIdx.y == 0 && dout) dout[(size_t)(b0 + b_l) * 160 + j] = a;
            ins[idx] = a * maskY[(b0 + b_l) * 10 + (j >> 4)];
        }
    } else {
        for (int idx = threadIdx.x; idx < 4 * K; idx += 256) {
            float v = in[(size_t)b0 * K + idx];
            if (maskY) {
                const int b_l = idx / K, j = idx % K;
                v *= maskY[(b0 + b_l) * 10 + (j >> 4)];
            }
            ins[idx] = v;
        }
    }
    __syncthreads();
    if (n < N) {
        float a0 = 0.f, a1 = 0.f, a2 = 0.f, a3 = 0.f;
        for (int k = 0; k < K; ++k) {
            const float wvv = w[(size_t)k * N + n];
            a0 += ins[k] * wvv;
            a1 += ins[K + k] * wvv;
            a2 += ins[2 * K + k] * wvv;
            a3 += ins[3 * K + k] * wvv;
        }
        const float bv = bias[n];
        float v[4] = {a0 + bv, a1 + bv, a2 + bv, a3 + bv};
        #pragma unroll
        for (int j = 0; j < 4; ++j) {
            float xv = v[j];
            xv = (mode == 0) ? fmaxf(xv, 0.f) : 1.f / (1.f + __expf(-xv));
            outp[(size_t)(b0 + j) * N + n] = xv;
        }
    }
}

// ============================================================
extern "C" void kernel_launch(void* const* d_in, const int* in_sizes, int n_in,
                              void* d_out, int out_size, void* d_ws, size_t ws_size,
                              hipStream_t stream) {
    const float* x   = (const float*)d_in[0];
    const float* y   = (const float*)d_in[1];
    const float* c1w = (const float*)d_in[2];
    const float* c1b = (const float*)d_in[3];
    const float* pw  = (const float*)d_in[4];
    const float* pb  = (const float*)d_in[5];
    const float* dw  = (const float*)d_in[6];
    const float* db  = (const float*)d_in[7];
    const float* w1  = (const float*)d_in[8];
    const float* b1  = (const float*)d_in[9];
    const float* w2  = (const float*)d_in[10];
    const float* b2  = (const float*)d_in[11];
    const float* w3  = (const float*)d_in[12];
    const float* b3  = (const float*)d_in[13];
    float* out = (float*)d_out;
    char* ws = (char*)d_ws;

    static const int exp_sizes[14] = {200704, 2560, 20736, 256, 5308416, 256,
                                      1474560, 160, 81920, 512, 524288, 1024,
                                      802816, 784};
    int bad = (n_in == 14) ? -1 : -2;
    if (bad == -1)
        for (int i = 0; i < 14; ++i) if (in_sizes[i] != exp_sizes[i]) { bad = i; break; }
    if (bad != -1) {
        fill_sentinel<<<(out_size + 255) / 256, 256, 0, stream>>>(out, out_size,
            7168.f + 16.f * (float)(bad + 1));
        return;
    }
    const size_t NEEDED = 72482816ULL;
    if (ws_size < NEEDED) {
        fill_sentinel<<<(out_size + 255) / 256, 256, 0, stream>>>(out, out_size, 111.0f);
        return;
    }

    // Phase A (conv/GEMM): h + wT2 + x3m (wc1b in x3m tail, re-zeroed pre-prim)
    u16*   h       = (u16*)(ws);                    // [0, 52,428,800)
    u16*   wT2     = (u16*)(ws + 52428800);         // [52,428,800, 63,045,632)
    float* x3m     = (float*)(ws + 63045632);       // [63,045,632, 72,482,816)
    u16*   wc1b    = (u16*)(ws + 72433664);         // last 49,152 B of x3m
    // Phase B (routing/recon), h/wT2 dead post-prim:
    u16*   votes   = (u16*)(ws);                    // 47,185,920
    float* preactD = (float*)(ws + 59146240);       //  3x163,840 -> 59,637,760
    u16*   dwb_t   = (u16*)(ws + 59637760);         //  2,949,120 -> 62,586,880
    float* r1      = (float*)(ws + 62586880);       //    524,288 -> 63,111,168 (post-routing)
    float* r2      = (float*)(ws + 63111168);       //  1,048,576 -> 64,159,744 (post-routing)

    prep1<<<2549, 256, 0, stream>>>(pw, wT2, x3m, c1w, wc1b);
    conv1_mfma<<<800, 256, 0, stream>>>(x, wc1b, c1b, h);
    hipMemsetAsync(wc1b, 0, 49152, stream);          // wc1b dead -> zero x3m tail for atomics
    prim_gemm_split<<<dim3(72, 6), 256, 0, stream>>>(h, wT2, x3m);
    prep2<<<5880, 256, 0, stream>>>(dw, dwb_t, preactD);

    float* pD2 = preactD + 81920;
    for (int half = 0; half < 2; ++half) {
        const int hb = half * 128;
        votes_gemm<<<dim3(144, 2), 192, 0, stream>>>(x3m, pb, dwb_t, votes, hb);
        routing_all<<<128, 512, 0, stream>>>(votes, db, pD2, hb);
    }

    // reconstruction; layer 1 fuses final squash + digit output
    mlp_layer<<<dim3(64, 2), 256, 0, stream>>>(pD2, y, w1, b1, r1, 160, 512, 0, db, out);
    mlp_layer<<<dim3(64, 4), 256, 0, stream>>>(r1, (float*)nullptr, w2, b2, r2, 512, 1024, 0,
                                               (const float*)nullptr, (float*)nullptr);
    mlp_layer<<<dim3(64, 4), 256, 0, stream>>>(r2, (float*)nullptr, w3, b3, out + 40960, 1024, 784, 1,
                                               (const float*)nullptr, (float*)nullptr);
}

// Round 14
// 685.922 us; speedup vs baseline: 1.2762x; 1.2762x over previous
//
#include <hip/hip_runtime.h>
#include <hip/hip_bf16.h>

typedef unsigned short u16;
typedef unsigned int u32;

static __device__ __forceinline__ float us2f(u16 u) {
    return __uint_as_float(((u32)u) << 16);
}
static __device__ __forceinline__ u16 f2bu(float f) {  // RNE
    u32 u = __float_as_uint(f);
    return (u16)((u + 0x7fffu + ((u >> 16) & 1u)) >> 16);
}

typedef __attribute__((ext_vector_type(8))) __bf16 bf16x8;
typedef __attribute__((ext_vector_type(4))) float f32x4;

// async global->LDS DMA, 16B per lane. LDS dest must be wave-uniform base;
// HW writes lane l at base + l*16 (linear).
static __device__ __forceinline__ void async16(const u16* g, u16* l) {
    __builtin_amdgcn_global_load_lds(
        (const __attribute__((address_space(1))) unsigned int*)g,
        (__attribute__((address_space(3))) unsigned int*)l, 16, 0, 0);
}

__global__ void fill_sentinel(float* out, int n, float val) {
    int g = blockIdx.x * 256 + threadIdx.x;
    if (g < n) out[g] = val;
}

// ============================================================
// prep1: transpose prim_w (blocks 0..255) + zero x3m head (2292 blocks)
// + build conv1 MFMA weights wc1b [3][256][32] bf16 (block 2548).
// ============================================================
__global__ __launch_bounds__(256) void prep1(const float* __restrict__ pw,
    u16* __restrict__ wt, float* __restrict__ x3m,
    const float* __restrict__ c1w, u16* __restrict__ wc1b)
{
    __shared__ u16 wl[81 * 258];
    const int bid = blockIdx.x, tid = threadIdx.x;
    if (bid < 256) {
        const float* ws = pw + (size_t)bid * 20736;
        for (int idx = tid; idx < 20736; idx += 256) {
            const int cc = idx / 81, kk = idx - cc * 81;
            wl[kk * 258 + cc] = f2bu(ws[idx]);
        }
        __syncthreads();
        u16* wo = wt + (size_t)bid * 20736;
        for (int q = tid; q < 20736; q += 256)
            wo[q] = wl[(q >> 8) * 258 + (q & 255)];
    } else if (bid < 2548) {
        float4 z = {0.f, 0.f, 0.f, 0.f};
        reinterpret_cast<float4*>(x3m)[(size_t)(bid - 256) * 256 + tid] = z;
    } else {
        for (int idx = tid; idx < 24576; idx += 256) {
            const int s = idx >> 13, rem = idx & 8191;
            const int n = rem >> 5, kk = rem & 31;
            const int k = s * 32 + kk;
            wc1b[idx] = (k < 81) ? f2bu(c1w[n * 81 + k]) : (u16)0;
        }
    }
}

// ============================================================
// prep2 (post-prim): dw->bf16 + zero preactD (incl. pD0 accumulated by
// votes_gemm's fused uniform-route pass).
// ============================================================
__global__ __launch_bounds__(256) void prep2(const float* __restrict__ dw,
    u16* __restrict__ dwb_t, float* __restrict__ preactD)
{
    const int bid = blockIdx.x, tid = threadIdx.x;
    if (bid < 5760) {
        const int g = bid * 256 + tid;   // 1,474,560
        dwb_t[g] = f2bu(dw[g]);
    } else {
        float4 z = {0.f, 0.f, 0.f, 0.f};
        reinterpret_cast<float4*>(preactD)[(size_t)(bid - 5760) * 256 + tid] = z;
    }
}

// ============================================================
// Kernel 1 (r11, verified): conv1 via MFMA, hi+lo bf16 split.
// ============================================================
__global__ __launch_bounds__(256, 2) void conv1_mfma(const float* __restrict__ x,
    const u16* __restrict__ wc1b, const float* __restrict__ bias, u16* __restrict__ h)
{
    __shared__ float xs[1568];
    const int tid = threadIdx.x;
    const int mBase = blockIdx.x * 128;          // 800 blocks
    const int b0 = mBase / 400;
    const int lane = tid & 63, wv = tid >> 6;
    const int wm = wv >> 1, wn = wv & 1;
    const int lcol = lane & 15, lquad = lane >> 4;

    {   // stage the (<=2) source images
        const int b1 = (b0 + 1 < 256) ? b0 + 1 : b0;
        for (int i = tid; i < 784; i += 256) {
            xs[i] = x[b0 * 784 + i];
            xs[784 + i] = x[b1 * 784 + i];
        }
    }
    __syncthreads();

    float bj[8];
    #pragma unroll
    for (int j = 0; j < 8; ++j) bj[j] = bias[wn * 128 + j * 16 + lcol];

    int xbase[4];
    #pragma unroll
    for (int i = 0; i < 4; ++i) {
        const int m = mBase + wm * 64 + i * 16 + lcol;
        const int img = (m / 400) - b0;
        const int rr = m % 400;
        const int iy = rr / 20, ix = rr - iy * 20;
        xbase[i] = img * 784 + iy * 28 + ix;
    }

    f32x4 acc[4][8];
    #pragma unroll
    for (int i = 0; i < 4; ++i)
        #pragma unroll
        for (int j = 0; j < 8; ++j) acc[i][j] = (f32x4){0.f, 0.f, 0.f, 0.f};

    #pragma unroll 1
    for (int s = 0; s < 3; ++s) {
        bf16x8 bfr[8];
        const u16* bp = wc1b + s * 8192 + (wn * 128 + lcol) * 32 + lquad * 8;
        #pragma unroll
        for (int j = 0; j < 8; ++j)
            bfr[j] = *reinterpret_cast<const bf16x8*>(bp + j * 512);

        bf16x8 ah[4], al[4];
        #pragma unroll
        for (int i = 0; i < 4; ++i) {
            union { bf16x8 v; u16 u[8]; } H, L;
            #pragma unroll
            for (int e = 0; e < 8; ++e) {
                int k = s * 32 + lquad * 8 + e;
                if (k > 80) k = 0;
                const int dy = k / 9, dx = k - dy * 9;
                const float xv = xs[xbase[i] + dy * 28 + dx];
                const u16 hu = f2bu(xv);
                H.u[e] = hu;
                L.u[e] = f2bu(xv - us2f(hu));
            }
            ah[i] = H.v; al[i] = L.v;
        }
        #pragma unroll
        for (int i = 0; i < 4; ++i)
            #pragma unroll
            for (int j = 0; j < 8; ++j) {
                acc[i][j] = __builtin_amdgcn_mfma_f32_16x16x32_bf16(ah[i], bfr[j], acc[i][j], 0, 0, 0);
                acc[i][j] = __builtin_amdgcn_mfma_f32_16x16x32_bf16(al[i], bfr[j], acc[i][j], 0, 0, 0);
            }
    }

    #pragma unroll
    for (int i = 0; i < 4; ++i) {
        const int mrow = mBase + wm * 64 + i * 16 + lquad * 4;
        #pragma unroll
        for (int j = 0; j < 8; ++j) {
            const int ncol = wn * 128 + j * 16 + lcol;
            #pragma unroll
            for (int r = 0; r < 4; ++r)
                h[(size_t)(mrow + r) * 256 + ncol] = f2bu(fmaxf(acc[i][j][r] + bj[j], 0.f));
        }
    }
}

// ============================================================
// Kernel 4: primary-caps GEMM — r5 config (156 us, verified x6 runs).
// prim is at its structural floor; frozen.
// ============================================================
__global__ __launch_bounds__(256, 2) void prim_gemm_split(const u16* __restrict__ h,
    const u16* __restrict__ wT, float* __restrict__ pm)
{
    __shared__ u16 As[3 * 4096];   // 3 x 8 KB  (128 rows x 32 u16)
    __shared__ u16 Bs[3 * 8192];   // 3 x 16 KB (256 rows x 32 u16)
    const int tid = threadIdx.x;
    const int split = blockIdx.y;
    const int mBase = blockIdx.x * 128;          // 72 m-tiles
    const int lane = tid & 63, wv = tid >> 6;
    const int swzq = (tid & 3) ^ ((lane >> 3) & 3);
    const int rA = wv * 32 + (lane >> 2);
    const int rB = wv * 64 + (lane >> 2);
    int mA0 = mBase + rA;
    int bA0 = mA0 / 36, rr0 = mA0 % 36;
    const int aBase0 = ((bA0 * 20 + 2 * (rr0 / 6)) * 20 + 2 * (rr0 % 6)) * 256 + swzq * 8;
    int mA1 = mA0 + 16;
    int bA1 = mA1 / 36, rr1 = mA1 % 36;
    const int aBase1 = ((bA1 * 20 + 2 * (rr1 / 6)) * 20 + 2 * (rr1 % 6)) * 256 + swzq * 8;
    const u16* bp0 = wT + (size_t)rB * 20736 + swzq * 8;

    int kglob = split * 3456;                  // 20736 / 6
    int ky = kglob / 2304; int krem = kglob - ky * 2304;
    int kx = krem >> 8; int c0 = krem & 255;

    f32x4 acc[4][8];
    #pragma unroll
    for (int i = 0; i < 4; ++i)
        #pragma unroll
        for (int j = 0; j < 8; ++j) acc[i][j] = (f32x4){0.f, 0.f, 0.f, 0.f};

    const int wm = wv >> 1, wn = wv & 1;
    const int lcol = lane & 15, lquad = lane >> 4;
    const int rswz = (lquad ^ ((lcol >> 1) & 3)) * 8;
    const u16* Arow = As + (wm * 64 + lcol) * 32 + rswz;
    const u16* Brow = Bs + (wn * 128 + lcol) * 32 + rswz;
    u16* aD = As + wv * 1024;
    u16* bD = Bs + wv * 2048;

    #define STAGE(sel)  do {                                                   \
        const int koffA = (ky * 20 + kx) * 256 + c0;                           \
        async16(h + aBase0 + koffA, aD + (sel) * 4096);                        \
        async16(h + aBase1 + koffA, aD + (sel) * 4096 + 512);                  \
        async16(bp0 + kglob,          bD + (sel) * 8192);                      \
        async16(bp0 + 331776 + kglob, bD + (sel) * 8192 + 512);               \
        async16(bp0 + 663552 + kglob, bD + (sel) * 8192 + 1024);              \
        async16(bp0 + 995328 + kglob, bD + (sel) * 8192 + 1536);              \
        kglob += 32; c0 += 32;                                                 \
        if (c0 == 256) { c0 = 0; if (++kx == 9) { kx = 0; ++ky; } }            \
    } while (0)

    #define COMPUTE(sel)  do {                                                 \
        const u16* Ab = Arow + (sel) * 4096;                                   \
        const u16* Bb = Brow + (sel) * 8192;                                   \
        bf16x8 af[4], bfr[8];                                                  \
        _Pragma("unroll")                                                      \
        for (int i = 0; i < 4; ++i)                                            \
            af[i] = *reinterpret_cast<const bf16x8*>(Ab + i * 512);            \
        _Pragma("unroll")                                                      \
        for (int j = 0; j < 8; ++j)                                            \
            bfr[j] = *reinterpret_cast<const bf16x8*>(Bb + j * 512);           \
        __builtin_amdgcn_s_setprio(1);                                         \
        _Pragma("unroll")                                                      \
        for (int i = 0; i < 4; ++i)                                            \
            _Pragma("unroll")                                                  \
            for (int j = 0; j < 8; ++j)                                        \
                acc[i][j] = __builtin_amdgcn_mfma_f32_16x16x32_bf16(af[i], bfr[j], acc[i][j], 0, 0, 0); \
        __builtin_amdgcn_s_setprio(0);                                         \
    } while (0)

    // 108 tiles. Prologue: tiles 0,1 -> bufs 0,1 (12 DMAs in flight).
    STAGE(0);
    STAGE(1);
    int cb = 0, sb = 2;
    #pragma unroll 1
    for (int kt = 0; kt < 106; ++kt) {
        STAGE(sb);                                        // tile kt+2 (18 in flight)
        asm volatile("s_waitcnt vmcnt(12)" ::: "memory"); // 6 oldest (tile kt) done
        __builtin_amdgcn_s_barrier();
        __builtin_amdgcn_sched_barrier(0);
        COMPUTE(cb);
        __builtin_amdgcn_sched_barrier(0);
        __builtin_amdgcn_s_barrier();
        __builtin_amdgcn_sched_barrier(0);
        cb = (cb == 2) ? 0 : cb + 1;
        sb = (sb == 2) ? 0 : sb + 1;
    }
    asm volatile("s_waitcnt vmcnt(6)" ::: "memory");
    __builtin_amdgcn_s_barrier();
    __builtin_amdgcn_sched_barrier(0);
    COMPUTE(1);
    __builtin_amdgcn_sched_barrier(0);
    asm volatile("s_waitcnt vmcnt(0)" ::: "memory");
    __builtin_amdgcn_s_barrier();
    __builtin_amdgcn_sched_barrier(0);
    COMPUTE(2);
    #undef STAGE
    #undef COMPUTE

    #pragma unroll
    for (int i = 0; i < 4; ++i) {
        const int mrow = mBase + wm * 64 + i * 16 + lquad * 4;
        #pragma unroll
        for (int j = 0; j < 8; ++j) {
            const int ncol = wn * 128 + j * 16 + lcol;
            #pragma unroll
            for (int r = 0; r < 4; ++r)
                unsafeAtomicAdd(&pm[(size_t)(mrow + r) * 256 + ncol], acc[i][j][r]);
        }
    }
}

// ============================================================
// Kernel 6: votes materialization with FUSED squash + FUSED routing
// iteration 1 (r14): uniform route pD0[gb][ot] += 0.1 * sum_i votes.
// Each block's 8-i partial sum accumulated per b_l via one atomicAdd
// (pD0 zeroed by prep2). Removes the 2 mode=0 routing dispatches and
// one full votes re-read pass per half.
// ============================================================
__global__ __launch_bounds__(192) void votes_gemm(const float* __restrict__ x3m,
    const float* __restrict__ pb, const u16* __restrict__ dwb_t,
    u16* __restrict__ votes, float* __restrict__ pD0, int hb)
{
    __shared__ float dws[8 * 1280];    // [i_l][a][ot] 40 KB
    __shared__ float x3s[64 * 64];     // [b_l][i_l][a] 16 KB
    __shared__ float pbs[256];
    const int ic = blockIdx.x * 8, bc = blockIdx.y * 64;
    const int tid = threadIdx.x;
    for (int q = tid; q < 256; q += 192) pbs[q] = pb[q];
    for (int q = tid; q < 10240; q += 192)
        dws[q] = us2f(dwb_t[(size_t)ic * 1280 + q]);
    __syncthreads();
    for (int g = tid; g < 512; g += 192) {
        const int b_l = g >> 3, i_l = g & 7;
        const int i = ic + i_l, cap = i / 36, p = i - cap * 36;
        const float* src = &x3m[((size_t)(hb + bc + b_l) * 36 + p) * 256 + cap * 8];
        float v[8]; float n2 = 0.f;
        #pragma unroll
        for (int a = 0; a < 8; ++a) {
            v[a] = src[a] * (1.f / 32.f) + pbs[cap * 8 + a];
            n2 += v[a] * v[a];
        }
        const float scale = (n2 / (1.f + n2)) * rsqrtf(n2 + 1e-9f);
        #pragma unroll
        for (int a = 0; a < 8; ++a)
            x3s[b_l * 64 + i_l * 8 + a] = v[a] * scale;
    }
    __syncthreads();
    if (tid < 160) {
        const int ot = tid;
        float dwr[8][8];
        #pragma unroll
        for (int i_l = 0; i_l < 8; ++i_l)
            #pragma unroll
            for (int a = 0; a < 8; ++a)
                dwr[i_l][a] = dws[i_l * 1280 + a * 160 + ot];
        #pragma unroll 1
        for (int b_l = 0; b_l < 64; ++b_l) {
            u16 ob[8];
            float s01 = 0.f;
            #pragma unroll
            for (int i_l = 0; i_l < 8; ++i_l) {
                const float* xp = &x3s[b_l * 64 + i_l * 8];
                float v = 0.f;
                #pragma unroll
                for (int a = 0; a < 8; ++a) v += xp[a] * dwr[i_l][a];
                ob[i_l] = f2bu(v);
                s01 += v;
            }
            uint4 o4;
            o4.x = (u32)ob[0] | ((u32)ob[1] << 16);
            o4.y = (u32)ob[2] | ((u32)ob[3] << 16);
            o4.z = (u32)ob[4] | ((u32)ob[5] << 16);
            o4.w = (u32)ob[6] | ((u32)ob[7] << 16);
            *reinterpret_cast<uint4*>(&votes[((size_t)(bc + b_l) * 160 + ot) * 1152 + ic]) = o4;
            unsafeAtomicAdd(&pD0[(size_t)(hb + bc + b_l) * 160 + ot], 0.1f * s01);
        }
    }
}

// ============================================================
// Kernel 7: FUSED routing iteration (r11-verified). grid (8, 128).
// mode: 1 = squash(pD_prev), logits = upd, route -> pD_next;
//       2 = squash(pD_prev), logits += upd, route -> pD_next.
// ============================================================
__global__ __launch_bounds__(256) void routing_fused(const u16* __restrict__ votes,
    const float* __restrict__ pD_prev, const float* __restrict__ db,
    float* __restrict__ logits, float* __restrict__ pD_next, int hb, int mode)
{
    __shared__ u16 vs16[160 * 146];        // 46,720 B
    __shared__ float route_s[144 * 10];    // 5,760 B
    __shared__ float act_s[160];
    const int ic = blockIdx.x * 144, b_l = blockIdx.y, gb = hb + b_l;
    const int tid = threadIdx.x;

    for (int q = tid; q < 2880; q += 256) {          // 160 ot x 18 chunks of 8 u16
        const int ot = q / 18, ch = q - ot * 18;
        const uint4 d = *reinterpret_cast<const uint4*>(
            &votes[((size_t)b_l * 160 + ot) * 1152 + ic + ch * 8]);
        u32* vp = reinterpret_cast<u32*>(&vs16[ot * 146 + ch * 8]);
        vp[0] = d.x; vp[1] = d.y; vp[2] = d.z; vp[3] = d.w;
    }
    if (tid < 160) {
        float pre = pD_prev[(size_t)gb * 160 + tid] + db[tid];
        float sq = pre * pre;
        sq += __shfl_xor(sq, 1); sq += __shfl_xor(sq, 2);
        sq += __shfl_xor(sq, 4); sq += __shfl_xor(sq, 8);
        act_s[tid] = pre * (sq / (1.f + sq)) * rsqrtf(sq + 1e-9f);
    }
    __syncthreads();

    if (tid < 144) {
        float acc[10];
        #pragma unroll
        for (int k = 0; k < 10; ++k) acc[k] = 0.f;
        #pragma unroll 4
        for (int ot = 0; ot < 160; ++ot)
            acc[ot >> 4] += us2f(vs16[ot * 146 + tid]) * act_s[ot];
        float* lp = &logits[((size_t)gb * 1152 + ic + tid) * 10];
        float l[10];
        if (mode == 1) {
            #pragma unroll
            for (int k = 0; k < 10; ++k) { l[k] = acc[k]; lp[k] = l[k]; }
        } else {
            #pragma unroll
            for (int k = 0; k < 10; ++k) { l[k] = lp[k] + acc[k]; lp[k] = l[k]; }
        }
        float mx = -1e30f;
        #pragma unroll
        for (int k = 0; k < 10; ++k) mx = fmaxf(mx, l[k]);
        float s = 0.f;
        #pragma unroll
        for (int k = 0; k < 10; ++k) { l[k] = __expf(l[k] - mx); s += l[k]; }
        const float inv = 1.f / s;
        #pragma unroll
        for (int k = 0; k < 10; ++k) route_s[tid * 10 + k] = l[k] * inv;
    }
    __syncthreads();

    if (tid < 160) {
        const int o = tid >> 4;
        const u16* vrow = &vs16[tid * 146];
        float acc2 = 0.f;
        const float* rp = &route_s[o];
        #pragma unroll 8
        for (int i = 0; i < 144; ++i)
            acc2 += rp[i * 10] * us2f(vrow[i]);
        unsafeAtomicAdd(&pD_next[(size_t)gb * 160 + tid], acc2);
    }
}

// ============================================================
// Kernel 10: dense layer, 4 rows/block. When db2 != nullptr, layer-1
// mode — in = RAW pD2; squash computed inline; digit written to dout
// by blockIdx.y==0 blocks.
// ============================================================
__global__ __launch_bounds__(256) void mlp_layer(const float* __restrict__ in,
    const float* __restrict__ maskY, const float* __restrict__ w,
    const float* __restrict__ bias, float* __restrict__ outp, int K, int N, int mode,
    const float* __restrict__ db2, float* __restrict__ dout)
{
    __shared__ float ins[4 * 1024];
    __shared__ float scl[40];
    const int b0 = blockIdx.x * 4;
    const int n = blockIdx.y * 256 + threadIdx.x;
    if (db2) {
        if (threadIdx.x < 40) {
            const int b_l = threadIdx.x / 10, o = threadIdx.x - b_l * 10;
            const float* pp = &in[(size_t)(b0 + b_l) * 160 + o * 16];
            float n2 = 0.f;
            #pragma unroll
            for (int t = 0; t < 16; ++t) {
                float pv = pp[t] + db2[o * 16 + t];
                n2 += pv * pv;
            }
            scl[threadIdx.x] = (n2 / (1.f + n2)) * rsqrtf(n2 + 1e-9f);
        }
        __syncthreads();
        for (int idx = threadIdx.x; idx < 4 * 160; idx += 256) {
            const int b_l = idx / 160, j = idx - b_l * 160;
            float a = (in[(size_t)(b0 + b_l) * 160 + j] + db2[j]) * scl[b_l * 10 + (j >> 4)];
            if (blockIdx.y == 0 && dout) dout[(size_t)(b0 + b_l) * 160 + j] = a;
            ins[idx] = a * maskY[(b0 + b_l) * 10 + (j >> 4)];
        }
    } else {
        for (int idx = threadIdx.x; idx < 4 * K; idx += 256) {
            float v = in[(size_t)b0 * K + idx];
            if (maskY) {
                const int b_l = idx / K, j = idx % K;
                v *= maskY[(b0 + b_l) * 10 + (j >> 4)];
            }
            ins[idx] = v;
        }
    }
    __syncthreads();
    if (n < N) {
        float a0 = 0.f, a1 = 0.f, a2 = 0.f, a3 = 0.f;
        for (int k = 0; k < K; ++k) {
            const float wvv = w[(size_t)k * N + n];
            a0 += ins[k] * wvv;
            a1 += ins[K + k] * wvv;
            a2 += ins[2 * K + k] * wvv;
            a3 += ins[3 * K + k] * wvv;
        }
        const float bv = bias[n];
        float v[4] = {a0 + bv, a1 + bv, a2 + bv, a3 + bv};
        #pragma unroll
        for (int j = 0; j < 4; ++j) {
            float xv = v[j];
            xv = (mode == 0) ? fmaxf(xv, 0.f) : 1.f / (1.f + __expf(-xv));
            outp[(size_t)(b0 + j) * N + n] = xv;
        }
    }
}

// ============================================================
extern "C" void kernel_launch(void* const* d_in, const int* in_sizes, int n_in,
                              void* d_out, int out_size, void* d_ws, size_t ws_size,
                              hipStream_t stream) {
    const float* x   = (const float*)d_in[0];
    const float* y   = (const float*)d_in[1];
    const float* c1w = (const float*)d_in[2];
    const float* c1b = (const float*)d_in[3];
    const float* pw  = (const float*)d_in[4];
    const float* pb  = (const float*)d_in[5];
    const float* dw  = (const float*)d_in[6];
    const float* db  = (const float*)d_in[7];
    const float* w1  = (const float*)d_in[8];
    const float* b1  = (const float*)d_in[9];
    const float* w2  = (const float*)d_in[10];
    const float* b2  = (const float*)d_in[11];
    const float* w3  = (const float*)d_in[12];
    const float* b3  = (const float*)d_in[13];
    float* out = (float*)d_out;
    char* ws = (char*)d_ws;

    static const int exp_sizes[14] = {200704, 2560, 20736, 256, 5308416, 256,
                                      1474560, 160, 81920, 512, 524288, 1024,
                                      802816, 784};
    int bad = (n_in == 14) ? -1 : -2;
    if (bad == -1)
        for (int i = 0; i < 14; ++i) if (in_sizes[i] != exp_sizes[i]) { bad = i; break; }
    if (bad != -1) {
        fill_sentinel<<<(out_size + 255) / 256, 256, 0, stream>>>(out, out_size,
            7168.f + 16.f * (float)(bad + 1));
        return;
    }
    const size_t NEEDED = 72482816ULL;
    if (ws_size < NEEDED) {
        fill_sentinel<<<(out_size + 255) / 256, 256, 0, stream>>>(out, out_size, 111.0f);
        return;
    }

    // Phase A (conv/GEMM): h + wT2 + x3m (wc1b in x3m tail, re-zeroed pre-prim)
    u16*   h       = (u16*)(ws);                    // [0, 52,428,800)
    u16*   wT2     = (u16*)(ws + 52428800);         // [52,428,800, 63,045,632)
    float* x3m     = (float*)(ws + 63045632);       // [63,045,632, 72,482,816)
    u16*   wc1b    = (u16*)(ws + 72433664);         // last 49,152 B of x3m
    // Phase B (routing/recon), h/wT2 dead post-prim:
    u16*   votes   = (u16*)(ws);                    // 47,185,920
    float* logits  = (float*)(ws + 47185920);       // 11,796,480 -> 58,982,400
    float* preactD = (float*)(ws + 59146240);       //  3x163,840 -> 59,637,760
    u16*   dwb_t   = (u16*)(ws + 59637760);         //  2,949,120 -> 62,586,880
    float* r1      = (float*)(ws + 62586880);       //    524,288 -> 63,111,168 (post-routing)
    float* r2      = (float*)(ws + 63111168);       //  1,048,576 -> 64,159,744 (post-routing)

    prep1<<<2549, 256, 0, stream>>>(pw, wT2, x3m, c1w, wc1b);
    conv1_mfma<<<800, 256, 0, stream>>>(x, wc1b, c1b, h);
    hipMemsetAsync(wc1b, 0, 49152, stream);          // wc1b dead -> zero x3m tail for atomics
    prim_gemm_split<<<dim3(72, 6), 256, 0, stream>>>(h, wT2, x3m);
    prep2<<<5880, 256, 0, stream>>>(dw, dwb_t, preactD);

    float* pD0 = preactD, *pD1 = preactD + 40960, *pD2 = preactD + 81920;
    for (int half = 0; half < 2; ++half) {
        const int hb = half * 128;
        // votes + fused squash + fused routing iter 1 (uniform route -> pD0)
        votes_gemm<<<dim3(144, 2), 192, 0, stream>>>(x3m, pb, dwb_t, votes, pD0, hb);
        // iter 2: squash(pD0); logits = upd; route; -> pD1
        routing_fused<<<dim3(8, 128), 256, 0, stream>>>(votes, pD0, db, logits, pD1, hb, 1);
        // iter 3: squash(pD1); logits += upd; route; -> pD2
        routing_fused<<<dim3(8, 128), 256, 0, stream>>>(votes, pD1, db, logits, pD2, hb, 2);
    }

    // reconstruction; layer 1 fuses final squash + digit output
    mlp_layer<<<dim3(64, 2), 256, 0, stream>>>(pD2, y, w1, b1, r1, 160, 512, 0, db, out);
    mlp_layer<<<dim3(64, 4), 256, 0, stream>>>(r1, (float*)nullptr, w2, b2, r2, 512, 1024, 0,
                                               (const float*)nullptr, (float*)nullptr);
    mlp_layer<<<dim3(64, 4), 256, 0, stream>>>(r2, (float*)nullptr, w3, b3, out + 40960, 1024, 784, 1,
                                               (const float*)nullptr, (float*)nullptr);
}